// Round 8
// baseline (152.400 us; speedup 1.0000x reference)
//
#include <hip/hip_runtime.h>

#define BB 4
#define NN 2048
#define FF 128
#define ALPHA 0.2f
#define NEG_BIG -9000000000000000.0f
#define SHIFT_C 16.0f  // exp(x-16): x=LR(f1+f2) bounded ~|10|; masked -> exp(-9e15)=0

typedef short bf16x8 __attribute__((ext_vector_type(8)));
typedef short bf16x4 __attribute__((ext_vector_type(4)));
typedef float f32x4 __attribute__((ext_vector_type(4)));

__device__ inline short f2bf(float f) {  // RNE float -> bf16 bits
    union { float f; unsigned u; } v; v.f = f;
    unsigned r = (v.u + 0x7FFFu + ((v.u >> 16) & 1u)) >> 16;
    return (short)r;
}
__device__ inline float bf2f(short s) {
    union { float f; unsigned u; } v;
    v.u = ((unsigned)(unsigned short)s) << 16;
    return v.f;
}

// ---------------------------------------------------------------------------
// k_wh: VERBATIM round 7 (passed): fused f12 + fp32 GEMM + split-bf16
// transposed store. 32 rows/block, 256 threads, grid 256.
// ---------------------------------------------------------------------------
__global__ __launch_bounds__(256) void k_wh(const float* __restrict__ h,
                                            const float* __restrict__ W,
                                            const float* __restrict__ a,
                                            short* __restrict__ WhHiT,
                                            short* __restrict__ WhLoT,
                                            float* __restrict__ f1,
                                            float* __restrict__ f2) {
    __shared__ float Wa[2 * FF];
    __shared__ float hs[32 * 128];  // 16 KB
    int tid = threadIdx.x;
    int r0 = blockIdx.x * 32;

    {
        int fin = tid & 127;
        const float* av = (tid < 128) ? a : (a + FF);
        const float* wr = W + (size_t)fin * FF;
        float s = 0.f;
        for (int o = 0; o < FF; o += 4) {
            float4 wv = *(const float4*)(wr + o);
            float4 avv = *(const float4*)(av + o);
            s += wv.x * avv.x + wv.y * avv.y + wv.z * avv.z + wv.w * avv.w;
        }
        Wa[(tid < 128 ? 0 : FF) + fin] = s;
    }
    {
        const float4* src = (const float4*)(h + (size_t)r0 * FF);
        float4* dst = (float4*)hs;
#pragma unroll
        for (int it = 0; it < 4; ++it)
            dst[it * 256 + tid] = src[it * 256 + tid];
    }
    __syncthreads();

    {
        int w = tid >> 6, lane = tid & 63;
        float wa1_0 = Wa[lane], wa1_1 = Wa[lane + 64];
        float wa2_0 = Wa[FF + lane], wa2_1 = Wa[FF + lane + 64];
        for (int rr = 0; rr < 8; ++rr) {
            int rloc = w * 8 + rr;
            int row = r0 + rloc;
            float x0 = hs[rloc * FF + lane], x1 = hs[rloc * FF + lane + 64];
            float s1 = x0 * wa1_0 + x1 * wa1_1;
            float s2 = x0 * wa2_0 + x1 * wa2_1;
#pragma unroll
            for (int m = 32; m >= 1; m >>= 1) {
                s1 += __shfl_xor(s1, m, 64);
                s2 += __shfl_xor(s2, m, 64);
            }
            if (lane == 0) { f1[row] = s1; f2[row] = s2; }
        }
    }

    int f4 = (tid & 31) * 4;
    int rg = tid >> 5;
    float acc[4][4];
#pragma unroll
    for (int rr = 0; rr < 4; ++rr)
#pragma unroll
        for (int cc = 0; cc < 4; ++cc) acc[rr][cc] = 0.f;

    for (int k0 = 0; k0 < FF; k0 += 4) {
        float4 wv[4];
#pragma unroll
        for (int kk = 0; kk < 4; ++kk)
            wv[kk] = *(const float4*)(W + (size_t)(k0 + kk) * FF + f4);
        float4 hv[4];
#pragma unroll
        for (int rr = 0; rr < 4; ++rr)
            hv[rr] = *(const float4*)(hs + (rg * 4 + rr) * FF + k0);
#pragma unroll
        for (int rr = 0; rr < 4; ++rr) {
            float hk[4] = {hv[rr].x, hv[rr].y, hv[rr].z, hv[rr].w};
#pragma unroll
            for (int kk = 0; kk < 4; ++kk) {
                acc[rr][0] += hk[kk] * wv[kk].x;
                acc[rr][1] += hk[kk] * wv[kk].y;
                acc[rr][2] += hk[kk] * wv[kk].z;
                acc[rr][3] += hk[kk] * wv[kk].w;
            }
        }
    }
    int rloc = r0 + rg * 4;
    int b = rloc >> 11;
    int j = rloc & (NN - 1);
#pragma unroll
    for (int cc = 0; cc < 4; ++cc) {
        bf16x4 ph, pl;
#pragma unroll
        for (int k = 0; k < 4; ++k) {
            float v = acc[k][cc];
            short hi = f2bf(v);
            ph[k] = hi;
            pl[k] = f2bf(v - bf2f(hi));
        }
        size_t off = ((size_t)(b * FF + f4 + cc)) * NN + j;
        *(bf16x4*)(WhHiT + off) = ph;
        *(bf16x4*)(WhLoT + off) = pl;
    }
}

// ---------------------------------------------------------------------------
// k_attn: round-7 structure; ONE change: all 16 B-frag loads per c-iter are
// batched into register arrays (issued before the afrag build so the exp
// VALU hides their latency), then 16 MFMAs run against a single vmcnt drain.
// Fixes the VGPR=36 serialization (load->wait->MFMA x16 at ~350cy each).
// ---------------------------------------------------------------------------
__global__ __launch_bounds__(512) void k_attn(const short* __restrict__ WhHiT,
                                              const short* __restrict__ WhLoT,
                                              const int* __restrict__ adj,
                                              const float* __restrict__ f1,
                                              const float* __restrict__ f2,
                                              float* __restrict__ out) {
    __shared__ float obuf[4][2048];  // 32 KB
    __shared__ float row_s[8][16];
    __shared__ float row_inv[16];

    int tid = threadIdx.x;
    int b = blockIdx.x >> 7;           // 0..3
    int i0 = (blockIdx.x & 127) * 16;  // row-tile base
    int w = tid >> 6, lane = tid & 63; // w in 0..7

    const float* f2b = f2 + b * NN;

    int r_a = lane & 15;
    int kg = lane >> 4;
    int i = i0 + r_a;
    float f1i = f1[b * NN + i];
    const int* adjrow = adj + (size_t)i * NN;
    const short* baseH = WhHiT + ((size_t)b * FF + r_a) * NN;
    const short* baseL = WhLoT + ((size_t)b * FF + r_a) * NN;

    f32x4 acc[8];
#pragma unroll
    for (int n = 0; n < 8; ++n)
#pragma unroll
        for (int q = 0; q < 4; ++q) acc[n][q] = 0.f;
    float sp = 0.f;

    // prefetch c=0 adj/f2
    int jb0 = w * 256 + kg * 8;
    int4 pa0 = *(const int4*)(adjrow + jb0);
    int4 pa1 = *(const int4*)(adjrow + jb0 + 4);
    float4 pq0 = *(const float4*)(f2b + jb0);
    float4 pq1 = *(const float4*)(f2b + jb0 + 4);

    for (int c = 0; c < 8; ++c) {
        int jb = w * 256 + c * 32 + kg * 8;

        // ---- issue ALL 16 B-frag loads up front (independent, pipelined) ----
        const short* bh = baseH + jb;
        const short* bl = baseL + jb;
        bf16x8 fh[8], fl[8];
#pragma unroll
        for (int n = 0; n < 8; ++n) {
            fh[n] = *(const bf16x8*)(bh + (size_t)n * 16 * NN);
            fl[n] = *(const bf16x8*)(bl + (size_t)n * 16 * NN);
        }

        // ---- afrag build from prefetched regs (hides B-frag latency) ----
        int4 a0 = pa0, a1 = pa1;
        float4 q0 = pq0, q1 = pq1;
        int av[8] = {a0.x, a0.y, a0.z, a0.w, a1.x, a1.y, a1.z, a1.w};
        float qv[8] = {q0.x, q0.y, q0.z, q0.w, q1.x, q1.y, q1.z, q1.w};
        bf16x8 afrag;
#pragma unroll
        for (int t = 0; t < 8; ++t) {
            float x = f1i + qv[t];
            x = x > 0.f ? x : ALPHA * x;
            x = av[t] > 0 ? x : NEG_BIG;
            short pb = f2bf(__expf(x - SHIFT_C));
            sp += bf2f(pb);
            afrag[t] = pb;
        }

        // ---- prefetch next-iter adj/f2 (dummy wrap at c==7) ----
        int jb_n = w * 256 + ((c + 1) & 7) * 32 + kg * 8;
        pa0 = *(const int4*)(adjrow + jb_n);
        pa1 = *(const int4*)(adjrow + jb_n + 4);
        pq0 = *(const float4*)(f2b + jb_n);
        pq1 = *(const float4*)(f2b + jb_n + 4);

        // ---- 16 MFMAs against registered fragments ----
#pragma unroll
        for (int n = 0; n < 8; ++n) {
            acc[n] = __builtin_amdgcn_mfma_f32_16x16x32_bf16(afrag, fh[n], acc[n], 0, 0, 0);
            acc[n] = __builtin_amdgcn_mfma_f32_16x16x32_bf16(afrag, fl[n], acc[n], 0, 0, 0);
        }
    }

    // row sums: lanes {l, l+16, l+32, l+48} share row l&15
    sp += __shfl_xor(sp, 16, 64);
    sp += __shfl_xor(sp, 32, 64);
    if (lane < 16) row_s[w][lane] = sp;

    // ---- staged tree reduce of 8 wave-partials through obuf[0..3] ----
    if (w >= 4) {
#pragma unroll
        for (int n = 0; n < 8; ++n)
#pragma unroll
            for (int q = 0; q < 4; ++q)
                obuf[w - 4][(kg * 4 + q) * FF + n * 16 + r_a] = acc[n][q];
    }
    __syncthreads();
    if (tid < 16)
        row_inv[tid] = 1.0f / (row_s[0][tid] + row_s[1][tid] + row_s[2][tid] + row_s[3][tid] +
                               row_s[4][tid] + row_s[5][tid] + row_s[6][tid] + row_s[7][tid]);
    if (w < 4) {
#pragma unroll
        for (int n = 0; n < 8; ++n)
#pragma unroll
            for (int q = 0; q < 4; ++q)
                acc[n][q] += obuf[w][(kg * 4 + q) * FF + n * 16 + r_a];
    }
    __syncthreads();
    if (w == 2 || w == 3) {
#pragma unroll
        for (int n = 0; n < 8; ++n)
#pragma unroll
            for (int q = 0; q < 4; ++q)
                obuf[w - 2][(kg * 4 + q) * FF + n * 16 + r_a] = acc[n][q];
    }
    __syncthreads();
    if (w < 2) {
#pragma unroll
        for (int n = 0; n < 8; ++n)
#pragma unroll
            for (int q = 0; q < 4; ++q)
                acc[n][q] += obuf[w][(kg * 4 + q) * FF + n * 16 + r_a];
    }
    __syncthreads();
    if (w == 1) {
#pragma unroll
        for (int n = 0; n < 8; ++n)
#pragma unroll
            for (int q = 0; q < 4; ++q)
                obuf[1][(kg * 4 + q) * FF + n * 16 + r_a] = acc[n][q];
    }
    __syncthreads();
    if (w == 0) {
#pragma unroll
        for (int n = 0; n < 8; ++n)
#pragma unroll
            for (int q = 0; q < 4; ++q) {
                int o = (kg * 4 + q) * FF + n * 16 + r_a;
                obuf[0][o] = acc[n][q] + obuf[1][o];
            }
    }
    __syncthreads();

    // ---- epilogue: normalize + store (all 512 threads, one float4 each) ----
    {
        int e = tid * 4;  // 0..2044
        int row = e >> 7;
        float inv = row_inv[row];
        float4 v = *(const float4*)&obuf[0][e];
        float4 o;
        o.x = v.x * inv; o.y = v.y * inv; o.z = v.z * inv; o.w = v.w * inv;
        *(float4*)(out + ((size_t)b * NN + i0 + row) * FF + (e & 127)) = o;
    }
}

// ---------------------------------------------------------------------------
extern "C" void kernel_launch(void* const* d_in, const int* in_sizes, int n_in,
                              void* d_out, int out_size, void* d_ws, size_t ws_size,
                              hipStream_t stream) {
    const float* h   = (const float*)d_in[0];
    const int*   adj = (const int*)d_in[1];
    const float* W   = (const float*)d_in[2];
    const float* a   = (const float*)d_in[3];
    float* out = (float*)d_out;

    short* WhHiT = (short*)d_ws;                          // 2 MB
    short* WhLoT = WhHiT + (size_t)BB * FF * NN;          // 2 MB
    float* f1 = (float*)(WhLoT + (size_t)BB * FF * NN);   // 32 KB
    float* f2 = f1 + (size_t)BB * NN;                     // 32 KB (4.066 MB total, proven)

    k_wh<<<(BB * NN) / 32, 256, 0, stream>>>(h, W, a, WhHiT, WhLoT, f1, f2);
    k_attn<<<BB * (NN / 16), 512, 0, stream>>>(WhHiT, WhLoT, adj, f1, f2, out);
}